// Round 1
// baseline (49.011 us; speedup 1.0000x reference)
//
#include <hip/hip_runtime.h>

#define NDIM 1024
#define BATCH 16
#define BCHUNK 8   // batches per thread; grid.z = BATCH/BCHUNK

// Fused spatially-varying 3x3 filter:
//   K[p,i,j] = bias[p] + sum_{m,n} w[p,0,m,n] * image_pad[i+m, j+n]
//   y[b,i,j] = sum_{k,l} K[3k+l,i,j] * x_pad[b, i+k, j+l]
// Each thread: 4 consecutive j-pixels (float4), 1 row i, BCHUNK batches.
// K computed once per thread (amortized over BCHUNK outputs per pixel).
__global__ __launch_bounds__(256) void smallsm_fused(
    const float* __restrict__ image,
    const float* __restrict__ x,
    const float* __restrict__ w,
    const float* __restrict__ bias,
    float* __restrict__ out)
{
    const int N = NDIM;
    const int tx = threadIdx.x & 15;   // 16 threads in j (x4 pixels = 64 cols)
    const int ty = threadIdx.x >> 4;   // 16 threads in i
    const int j0 = (blockIdx.x * 16 + tx) * 4;
    const int i  = blockIdx.y * 16 + ty;
    const int b0 = blockIdx.z * BCHUNK;

    const bool jm_ok = (j0 > 0);
    const bool jp_ok = (j0 + 4 < N);

    // --- image patch: rows i-1..i+1, cols j0-1..j0+4 ---
    float im[3][6];
#pragma unroll
    for (int r = 0; r < 3; ++r) {
        const int row = i - 1 + r;
        const bool rv = (row >= 0) && (row < N);
        const float* rp = image + (size_t)row * N;
        im[r][0] = (rv && jm_ok) ? rp[j0 - 1] : 0.f;
        if (rv) {
            const float4 m = *reinterpret_cast<const float4*>(rp + j0);
            im[r][1] = m.x; im[r][2] = m.y; im[r][3] = m.z; im[r][4] = m.w;
        } else {
            im[r][1] = 0.f; im[r][2] = 0.f; im[r][3] = 0.f; im[r][4] = 0.f;
        }
        im[r][5] = (rv && jp_ok) ? rp[j0 + 4] : 0.f;
    }

    // --- per-pixel kernels K[9][4 pixels] ---
    float K[9][4];
#pragma unroll
    for (int p = 0; p < 9; ++p) {
        const float bv = bias[p];
        float a0 = bv, a1 = bv, a2 = bv, a3 = bv;
#pragma unroll
        for (int m = 0; m < 3; ++m) {
#pragma unroll
            for (int n = 0; n < 3; ++n) {
                const float wv = w[p * 9 + m * 3 + n];
                a0 += wv * im[m][0 + n];
                a1 += wv * im[m][1 + n];
                a2 += wv * im[m][2 + n];
                a3 += wv * im[m][3 + n];
            }
        }
        K[p][0] = a0; K[p][1] = a1; K[p][2] = a2; K[p][3] = a3;
    }

    // --- apply to BCHUNK batches ---
#pragma unroll 2
    for (int bb = 0; bb < BCHUNK; ++bb) {
        const size_t boff = (size_t)(b0 + bb) * N * N;
        const float* xb = x + boff;

        float xv[3][6];
#pragma unroll
        for (int r = 0; r < 3; ++r) {
            const int row = i - 1 + r;
            const bool rv = (row >= 0) && (row < N);
            const float* rp = xb + (size_t)row * N;
            xv[r][0] = (rv && jm_ok) ? rp[j0 - 1] : 0.f;
            if (rv) {
                const float4 m = *reinterpret_cast<const float4*>(rp + j0);
                xv[r][1] = m.x; xv[r][2] = m.y; xv[r][3] = m.z; xv[r][4] = m.w;
            } else {
                xv[r][1] = 0.f; xv[r][2] = 0.f; xv[r][3] = 0.f; xv[r][4] = 0.f;
            }
            xv[r][5] = (rv && jp_ok) ? rp[j0 + 4] : 0.f;
        }

        float a0 = 0.f, a1 = 0.f, a2 = 0.f, a3 = 0.f;
#pragma unroll
        for (int k = 0; k < 3; ++k) {
#pragma unroll
            for (int l = 0; l < 3; ++l) {
                const float* Kp = K[3 * k + l];
                a0 += Kp[0] * xv[k][0 + l];
                a1 += Kp[1] * xv[k][1 + l];
                a2 += Kp[2] * xv[k][2 + l];
                a3 += Kp[3] * xv[k][3 + l];
            }
        }

        float4 res; res.x = a0; res.y = a1; res.z = a2; res.w = a3;
        *reinterpret_cast<float4*>(out + boff + (size_t)i * N + j0) = res;
    }
}

extern "C" void kernel_launch(void* const* d_in, const int* in_sizes, int n_in,
                              void* d_out, int out_size, void* d_ws, size_t ws_size,
                              hipStream_t stream) {
    const float* image = (const float*)d_in[0];
    const float* x     = (const float*)d_in[1];
    const float* w     = (const float*)d_in[2];
    const float* bias  = (const float*)d_in[3];
    float* out = (float*)d_out;

    dim3 grid(NDIM / 64, NDIM / 16, BATCH / BCHUNK);
    dim3 block(256);
    hipLaunchKernelGGL(smallsm_fused, grid, block, 0, stream,
                       image, x, w, bias, out);
}